// Round 2
// baseline (501.945 us; speedup 1.0000x reference)
//
#include <hip/hip_runtime.h>
#include <hip/hip_bf16.h>

#define D_MODEL 1024
#define N_HEADS 16
#define HEAD_DIM 64
#define NUM_RULES 64
#define RANK 8
#define SHARED_RANK 32
#define NUM_BLOCKS_ 16
#define BB 4
#define SS 1024
#define NTOK (BB*SS)

__device__ __forceinline__ float bf2f(unsigned short u) {
  unsigned int i = ((unsigned int)u) << 16;
  float f;
  __builtin_memcpy(&f, &i, 4);
  return f;
}
__device__ __forceinline__ unsigned short f2bf(float f) {
  __hip_bfloat16 h = __float2bfloat16(f);
  unsigned short u;
  __builtin_memcpy(&u, &h, 2);
  return u;
}
template<bool BF>
__device__ __forceinline__ float ldw(const void* p, size_t i) {
  if (BF) return bf2f(((const unsigned short*)p)[i]);
  else    return ((const float*)p)[i];
}

// ---------------------------------------------------------------------------
// Dtype detection: bf16 data -> ~100% plausible bf16 exponents in first 256
// words; fp32 data -> ~58% (low mantissa halves are random bits).
// ---------------------------------------------------------------------------
__global__ void detect_kernel(const unsigned short* __restrict__ x, int* __restrict__ flag) {
  const int lane = threadIdx.x;  // 64
  int good = 0;
  for (int i = 0; i < 4; i++) {
    unsigned short u = x[lane*4 + i];
    int e = (u >> 7) & 0xFF;
    good += (e == 0 || (e >= 100 && e <= 145)) ? 1 : 0;
  }
  for (int off = 32; off; off >>= 1) good += __shfl_xor(good, off);
  if (lane == 0) flag[0] = (good >= 224) ? 1 : 0;
}

// ---------------------------------------------------------------------------
// Precompute: M[64][64] = (rqn . rkn)/tau  and sel[4][64][16] = softmax(lg*4)
// ---------------------------------------------------------------------------
template<bool BF>
__device__ __forceinline__ void precompute_body(
    const void* rq, const void* rk,
    const void* qlg, const void* klg, const void* vlg, const void* olg,
    float* __restrict__ M, float* __restrict__ sel)
{
  __shared__ float rqn[64][8], rkn[64][8];
  const int tid = threadIdx.x;  // 256
  if (tid < 64) {
    float v[8]; float s = 0.f;
    for (int i = 0; i < 8; i++) { v[i] = ldw<BF>(rq, tid*8+i); s += v[i]*v[i]; }
    float inv = 1.0f / fmaxf(sqrtf(s), 1e-12f);
    for (int i = 0; i < 8; i++) rqn[tid][i] = v[i]*inv;
  } else if (tid < 128) {
    int r = tid - 64;
    float v[8]; float s = 0.f;
    for (int i = 0; i < 8; i++) { v[i] = ldw<BF>(rk, r*8+i); s += v[i]*v[i]; }
    float inv = 1.0f / fmaxf(sqrtf(s), 1e-12f);
    for (int i = 0; i < 8; i++) rkn[r][i] = v[i]*inv;
  }
  __syncthreads();
  const float LN8 = 2.0794415416798357f;  // 1/tau = ln(8)
  for (int idx = tid; idx < 64*64; idx += 256) {
    int i = idx >> 6, j = idx & 63;
    float d = 0.f;
    for (int t = 0; t < 8; t++) d += rqn[i][t]*rkn[j][t];
    M[idx] = d * LN8;
  }
  const void* lgs[4] = {qlg, klg, vlg, olg};
  {
    int p = tid >> 6, r = tid & 63;
    const void* lg = lgs[p];
    float e[NUM_BLOCKS_]; float mx = -1e30f;
    for (int b = 0; b < NUM_BLOCKS_; b++) {
      e[b] = ldw<BF>(lg, r*NUM_BLOCKS_ + b) * 4.0f;
      mx = fmaxf(mx, e[b]);
    }
    float s = 0.f;
    for (int b = 0; b < NUM_BLOCKS_; b++) { e[b] = expf(e[b]-mx); s += e[b]; }
    float inv = 1.0f/s;
    for (int b = 0; b < NUM_BLOCKS_; b++) sel[tid*NUM_BLOCKS_+b] = e[b]*inv;
  }
}

__global__ void precompute_kernel(
    const void* rq, const void* rk,
    const void* qlg, const void* klg, const void* vlg, const void* olg,
    float* M, float* sel, const int* __restrict__ flag)
{
  if (*flag) precompute_body<true >(rq, rk, qlg, klg, vlg, olg, M, sel);
  else       precompute_body<false>(rq, rk, qlg, klg, vlg, olg, M, sel);
}

// ---------------------------------------------------------------------------
// Rule-aware projection: out[n] = x[n]@si@so + (lowrank blocks)*sel[rule]
// One block (256 threads) per token. Optional fused RoPE (q/k).
// ---------------------------------------------------------------------------
template<bool IN_BF, bool W_BF, bool OUT_BF>
__device__ __forceinline__ void proj_body(
    const void* __restrict__ xin_, const int* __restrict__ rules,
    const void* __restrict__ si, const void* __restrict__ so,
    const void* __restrict__ ri, const void* __restrict__ ro,
    const float* __restrict__ sel, void* __restrict__ out_, int do_rope)
{
  const int n = blockIdx.x;
  const int tid = threadIdx.x;
  __shared__ float xs[D_MODEL];
  __shared__ float tpart[8][SHARED_RANK];
  __shared__ float tt[SHARED_RANK];
  __shared__ float hh[NUM_BLOCKS_][RANK];
  __shared__ float selb[NUM_BLOCKS_];
  __shared__ float row[D_MODEL];

  if (IN_BF) {
    const ushort4* xr = (const ushort4*)((const unsigned short*)xin_ + (size_t)n*D_MODEL);
    ushort4 u = xr[tid];
    float4 f; f.x = bf2f(u.x); f.y = bf2f(u.y); f.z = bf2f(u.z); f.w = bf2f(u.w);
    ((float4*)xs)[tid] = f;
  } else {
    ((float4*)xs)[tid] = ((const float4*)xin_)[(size_t)n*(D_MODEL/4) + tid];
  }
  const int rule = rules[n];
  if (tid < NUM_BLOCKS_) selb[tid] = sel[rule*NUM_BLOCKS_ + tid];
  __syncthreads();

  // t[j] = sum_d x[d]*si[d][j]
  {
    const int j = tid & 31, c = tid >> 5;
    const float* xp = xs + c*128;
    float p = 0.f;
    for (int d = 0; d < 128; d++)
      p += xp[d] * ldw<W_BF>(si, (size_t)(c*128 + d)*SHARED_RANK + j);
    tpart[c][j] = p;
  }
  __syncthreads();
  if (tid < SHARED_RANK) {
    float s = 0.f;
    for (int c = 0; c < 8; c++) s += tpart[c][tid];
    tt[tid] = s;
  }
  __syncthreads();

  // base[ch] = sum_j t[j]*so[j][ch]
  float basev[4];
  for (int u = 0; u < 4; u++) {
    const int ch = tid + u*256;
    float s = 0.f;
    for (int j = 0; j < SHARED_RANK; j++)
      s += tt[j] * ldw<W_BF>(so, (size_t)j*D_MODEL + ch);
    basev[u] = s;
  }
  // h[blk][r] = sum_s x[blk*64+s]*ri[rule][s][r]
  if (tid < 128) {
    const int blk = tid >> 3, r = tid & 7;
    const float* xp = xs + blk*HEAD_DIM;
    float s = 0.f;
    for (int k = 0; k < HEAD_DIM; k++)
      s += xp[k] * ldw<W_BF>(ri, (size_t)rule*HEAD_DIM*RANK + (size_t)k*RANK + r);
    hh[blk][r] = s;
  }
  __syncthreads();
  // a[blk][t] = sum_r h[blk][r]*ro[rule][r][t]; row = base + a*sel[blk]
  for (int u = 0; u < 4; u++) {
    const int ch = tid + u*256;
    const int blk = ch >> 6, tc = ch & 63;
    float a = 0.f;
    for (int r = 0; r < RANK; r++)
      a += hh[blk][r] * ldw<W_BF>(ro, (size_t)rule*RANK*HEAD_DIM + (size_t)r*HEAD_DIM + tc);
    row[ch] = basev[u] + a * selb[blk];
  }
  __syncthreads();

  if (do_rope) {
    const int s_pos = n & (SS-1);
    for (int u = 0; u < 2; u++) {
      const int p = tid + u*256;             // pair index 0..511
      const int i = p & 31;
      float f = (float)s_pos * expf(-(float)(2*i) * (9.210340371976184f / 64.0f));
      float sn, cs;
      sincosf(f, &sn, &cs);
      const int c0 = (p >> 5)*HEAD_DIM + 2*i;
      float e = row[c0], o = row[c0+1];
      row[c0]   = e*cs - o*sn;
      row[c0+1] = o*cs + e*sn;
    }
    __syncthreads();
  }

  if (OUT_BF) {
    unsigned short* op = (unsigned short*)out_ + (size_t)n*D_MODEL;
    ushort4 u;
    u.x = f2bf(row[tid*4+0]); u.y = f2bf(row[tid*4+1]);
    u.z = f2bf(row[tid*4+2]); u.w = f2bf(row[tid*4+3]);
    ((ushort4*)op)[tid] = u;
  } else {
    ((float4*)out_)[(size_t)n*(D_MODEL/4) + tid] = ((float4*)row)[tid];
  }
}

__global__ __launch_bounds__(256) void proj_qkv_kernel(
    const void* x, const int* rules, const void* si, const void* so,
    const void* ri, const void* ro, const float* sel, float* out, int do_rope,
    const int* __restrict__ flag)
{
  if (*flag) proj_body<true, true, false>(x, rules, si, so, ri, ro, sel, (void*)out, do_rope);
  else       proj_body<false,false,false>(x, rules, si, so, ri, ro, sel, (void*)out, do_rope);
}

__global__ __launch_bounds__(256) void proj_o_kernel(
    const float* ain, const int* rules, const void* si, const void* so,
    const void* ri, const void* ro, const float* sel, void* out,
    const int* __restrict__ flag)
{
  if (*flag) proj_body<false,true, true >((const void*)ain, rules, si, so, ri, ro, sel, out, 0);
  else       proj_body<false,false,false>((const void*)ain, rules, si, so, ri, ro, sel, out, 0);
}

// ---------------------------------------------------------------------------
// Fused rule-mask + sparse attention. One block (256 thr) per (b, q) row;
// all 16 heads share the LDS allowed-key list.
// rule r allowed <=> #causal keys with strictly greater M value < 32.
// ---------------------------------------------------------------------------
__global__ __launch_bounds__(256) void attn_kernel(
    const float* __restrict__ qb, const float* __restrict__ kb, const float* __restrict__ vb,
    const int* __restrict__ rules, const float* __restrict__ M,
    float* __restrict__ outb)
{
  const int bid = blockIdx.x;              // b*1024 + qi
  const int b = bid >> 10, qi = bid & 1023;
  const int tid = threadIdx.x, lane = tid & 63, wv = tid >> 6;
  __shared__ int rrow[SS];
  __shared__ float val[64];
  __shared__ int cnt4[4][64];
  __shared__ unsigned short keys[SS];
  __shared__ float qsh[N_HEADS][HEAD_DIM];
  __shared__ int nkeys;

  for (int i = tid; i < SS; i += 256) rrow[i] = rules[b*SS + i];
  __syncthreads();
  const int qrule = rrow[qi];
  {
    int c = 0;
    for (int k = wv; k <= qi; k += 4) c += (rrow[k] == lane) ? 1 : 0;
    cnt4[wv][lane] = c;
  }
  if (tid < 64) val[tid] = M[qrule*64 + tid];
  const int nq = b*SS + qi;
  for (int hi = 0; hi < 4; hi++) {
    int h = wv*4 + hi;
    qsh[h][lane] = qb[(size_t)nq*D_MODEL + h*HEAD_DIM + lane] * 0.125f;
  }
  __syncthreads();

  if (wv == 0) {
    int c = cnt4[0][lane] + cnt4[1][lane] + cnt4[2][lane] + cnt4[3][lane];
    float myv = val[lane];
    int A = 0;
    for (int r = 0; r < 64; r++) {
      int cr = __shfl(c, r);
      A += (val[r] > myv) ? cr : 0;
    }
    unsigned long long allowed = __ballot(A < 32);
    int pos = 0;
    const unsigned long long lmask = (1ULL << lane) - 1ULL;
    for (int k0 = 0; k0 <= qi; k0 += 64) {
      int k = k0 + lane;
      int kc = (k <= qi) ? k : qi;
      bool ok = (k <= qi) && (((allowed >> rrow[kc]) & 1ULL) != 0ULL);
      unsigned long long bal = __ballot(ok);
      if (ok) keys[pos + __popcll(bal & lmask)] = (unsigned short)k;
      pos += __popcll(bal);
    }
    if (lane == 0) nkeys = pos;
  }
  __syncthreads();
  const int total = nkeys;

  const float* kbaseh = kb + (size_t)b*SS*D_MODEL;
  const float* vbaseh = vb + (size_t)b*SS*D_MODEL;
  for (int hi = 0; hi < 4; hi++) {
    const int h = wv*4 + hi;
    const float* kbase = kbaseh + h*HEAD_DIM;
    const float* vbase = vbaseh + h*HEAD_DIM + lane;
    const float* qs = qsh[h];
    float m = -1e30f, l = 0.f, acc = 0.f;
    for (int c0 = 0; c0 < total; c0 += 64) {
      int nc = total - c0; if (nc > 64) nc = 64;
      float s = -1e30f;
      if (lane < nc) {
        int key = keys[c0 + lane];
        const float4* kr = (const float4*)(kbase + (size_t)key*D_MODEL);
        float sum = 0.f;
        for (int t = 0; t < 16; t++) {
          float4 kv = kr[t];
          sum += qs[4*t]*kv.x + qs[4*t+1]*kv.y + qs[4*t+2]*kv.z + qs[4*t+3]*kv.w;
        }
        s = sum;
      }
      float cm = s;
      for (int off = 32; off; off >>= 1) cm = fmaxf(cm, __shfl_xor(cm, off));
      float newm = fmaxf(m, cm);
      float alpha = expf(m - newm);
      float w = (lane < nc) ? expf(s - newm) : 0.f;
      float lsum = w;
      for (int off = 32; off; off >>= 1) lsum += __shfl_xor(lsum, off);
      acc *= alpha;
      for (int i = 0; i < nc; i++) {
        float wi = __shfl(w, i);
        acc += wi * vbase[(size_t)keys[c0+i]*D_MODEL];
      }
      l = l*alpha + lsum;
      m = newm;
    }
    outb[(size_t)nq*D_MODEL + h*HEAD_DIM + lane] = acc / l;
  }
}

// ---------------------------------------------------------------------------
extern "C" void kernel_launch(void* const* d_in, const int* in_sizes, int n_in,
                              void* d_out, int out_size, void* d_ws, size_t ws_size,
                              hipStream_t stream) {
  (void)in_sizes; (void)n_in; (void)out_size; (void)ws_size;
  const void* x    = d_in[0];
  const int* rules = (const int*)d_in[1];
  const void* q_si = d_in[2];  const void* q_so = d_in[3];
  const void* q_ri = d_in[4];  const void* q_ro = d_in[5];  const void* q_lg = d_in[6];
  const void* k_si = d_in[7];  const void* k_so = d_in[8];
  const void* k_ri = d_in[9];  const void* k_ro = d_in[10]; const void* k_lg = d_in[11];
  const void* v_si = d_in[12]; const void* v_so = d_in[13];
  const void* v_ri = d_in[14]; const void* v_ro = d_in[15]; const void* v_lg = d_in[16];
  const void* o_si = d_in[17]; const void* o_so = d_in[18];
  const void* o_ri = d_in[19]; const void* o_ro = d_in[20]; const void* o_lg = d_in[21];
  const void* rq   = d_in[22]; const void* rk   = d_in[23];

  char* ws = (char*)d_ws;
  float* qb   = (float*)(ws);                               // 16 MB
  float* kb   = (float*)(ws + (size_t)16*1024*1024);        // 16 MB
  float* vb   = (float*)(ws + (size_t)32*1024*1024);        // 16 MB
  float* ab   = (float*)(ws + (size_t)48*1024*1024);        // 16 MB
  float* Mt   = (float*)(ws + (size_t)64*1024*1024);        // 16 KB
  float* selt = (float*)(ws + (size_t)64*1024*1024 + 16*1024);   // 16 KB
  int*   flag = (int*)  (ws + (size_t)64*1024*1024 + 32*1024);

  detect_kernel<<<1, 64, 0, stream>>>((const unsigned short*)x, flag);
  precompute_kernel<<<1, 256, 0, stream>>>(rq, rk, q_lg, k_lg, v_lg, o_lg, Mt, selt, flag);
  proj_qkv_kernel<<<NTOK, 256, 0, stream>>>(x, rules, q_si, q_so, q_ri, q_ro, selt,          qb, 1, flag);
  proj_qkv_kernel<<<NTOK, 256, 0, stream>>>(x, rules, k_si, k_so, k_ri, k_ro, selt + 1024,   kb, 1, flag);
  proj_qkv_kernel<<<NTOK, 256, 0, stream>>>(x, rules, v_si, v_so, v_ri, v_ro, selt + 2*1024, vb, 0, flag);
  attn_kernel<<<NTOK, 256, 0, stream>>>(qb, kb, vb, rules, Mt, ab);
  proj_o_kernel<<<NTOK, 256, 0, stream>>>(ab, rules, o_si, o_so, o_ri, o_ro, selt + 3*1024, d_out, flag);
}